// Round 19
// baseline (189.902 us; speedup 1.0000x reference)
//
#include <hip/hip_runtime.h>
#include <cstddef>

// Problem constants (from reference)
#define BB 64
#define NN 207
#define KK 32
#define CC 8
#define DIN 64
#define DOUT 64
#define TILE 16              // n-positions per block (best-known config)
#define NT ((NN + TILE - 1) / TILE)   // 13 tiles -> 13 x 64 = 832 blocks
#define MPAD 68              // mean row stride: phase-2 class rows 4 banks apart

__device__ __forceinline__ float fast_tanh(float v) {
    // tanh(v) = 1 - 2/(exp(2v)+1); ~1e-6 rel err, saturates correctly.
    float e = __expf(2.0f * v);
    return 1.0f - 2.0f * __builtin_amdgcn_rcpf(e + 1.0f);
}

// ---- kernel 0: W[C][DOUT][DIN] -> Wt[C][DIN][DOUT] (one class per block) ----
__global__ __launch_bounds__(256) void transpose_W_kernel(
    const float* __restrict__ W, float* __restrict__ Wt)
{
    __shared__ float t[DIN * (DOUT + 1)];   // +1 pad: conflict-free transpose
    const int c   = blockIdx.x;
    const int tid = threadIdx.x;
    const float* __restrict__ Wc  = W  + (size_t)c * DOUT * DIN;
    float* __restrict__       Wtc = Wt + (size_t)c * DIN * DOUT;
    #pragma unroll
    for (int r = 0; r < 16; ++r) {
        const int i = r * 256 + tid;        // i = o*DIN + d  (coalesced read)
        const int o = i >> 6, d = i & 63;
        t[d * (DOUT + 1) + o] = Wc[i];
    }
    __syncthreads();
    #pragma unroll
    for (int r = 0; r < 16; ++r) {
        const int i = r * 256 + tid;        // i = d*DOUT + o (coalesced write)
        const int d = i >> 6, o = i & 63;
        Wtc[i] = t[d * (DOUT + 1) + o];
    }
}

// ---- phase-1 helpers: wave-contiguous 1KB loads (the fill/µbench-fast shape) ----
// Load j of a position: 64 lanes x 16B = 1KB contiguous (covers k = 4j..4j+3).
__device__ __forceinline__ void pfw(float4 (&buf)[8], const float4* __restrict__ xp4,
                                    int lane) {
    #pragma unroll
    for (int j = 0; j < 8; ++j)
        buf[j] = xp4[j * 64 + lane];
}
// Accumulate: lane's chunk belongs to k = 4j + (lane>>4); mask-FMA over 8 classes.
__device__ __forceinline__ void cbw(float4 (&acc)[CC], const float4 (&buf)[8],
                                    const int* idx_row, int kofs) {
    #pragma unroll
    for (int j = 0; j < 8; ++j) {
        const int ca = idx_row[j * 4 + kofs];   // 16-lane broadcast LDS read
        #pragma unroll
        for (int c = 0; c < CC; ++c) {
            const float mf = (ca == c) ? 1.0f : 0.0f;
            acc[c].x = fmaf(mf, buf[j].x, acc[c].x);
            acc[c].y = fmaf(mf, buf[j].y, acc[c].y);
            acc[c].z = fmaf(mf, buf[j].z, acc[c].z);
            acc[c].w = fmaf(mf, buf[j].w, acc[c].w);
        }
    }
}
// Butterfly-sum the 4 k-groups (lanes xor 16, 32), scale, write mean rows.
__device__ __forceinline__ void reduce_write(float4 (&acc)[CC], const float* inv_row,
                                             float* mean_row_base, int lane, int d4) {
    #pragma unroll
    for (int c = 0; c < CC; ++c) {
        acc[c].x += __shfl_xor(acc[c].x, 16);
        acc[c].y += __shfl_xor(acc[c].y, 16);
        acc[c].z += __shfl_xor(acc[c].z, 16);
        acc[c].w += __shfl_xor(acc[c].w, 16);
        acc[c].x += __shfl_xor(acc[c].x, 32);
        acc[c].y += __shfl_xor(acc[c].y, 32);
        acc[c].z += __shfl_xor(acc[c].z, 32);
        acc[c].w += __shfl_xor(acc[c].w, 32);
    }
    if (lane < 16) {
        #pragma unroll
        for (int c = 0; c < CC; ++c) {
            const float s = inv_row[c];
            float4 m;
            m.x = acc[c].x * s; m.y = acc[c].y * s;
            m.z = acc[c].z * s; m.w = acc[c].w * s;
            *(float4*)(mean_row_base + (size_t)c * MPAD + d4) = m;
        }
    }
}

// ---- main kernel ----
// ONE change vs the 62.6us baseline: phase-1 x-loads are wave-contiguous 1KB
// per instruction (the shape fills/copy-ubench run at 6.3-6.9 TB/s) instead of
// 4 scattered 256B segments. Requires a 2-round shfl_xor reduce per position.
// Phase 2 unchanged. __launch_bounds__(256,2): 256-VGPR budget, no spill trap.
template<bool USE_WT>
__global__ __launch_bounds__(256, 2) void ordered_gcn_kernel(
    const int* __restrict__ idx,      // [B, N, K]
    const float* __restrict__ x,      // [B, N, K, DIN]
    const float* __restrict__ W,      // [C, DOUT, DIN]
    const float* __restrict__ Wt,     // [C, DIN, DOUT] (in d_ws)
    float* __restrict__ out)          // [B, N, C, DOUT]
{
    __shared__ int   idx_s[TILE * KK];          // 2 KB
    __shared__ float inv_s[TILE * CC];          // 512 B
    __shared__ float mean_s[TILE * CC * MPAD];  // 34816 B

    const int tid = threadIdx.x;
    const int b  = blockIdx.y;
    const int n0 = blockIdx.x * TILE;

    // ---- load idx tile: 512 ints, 2 per thread, coalesced ----
    #pragma unroll
    for (int r = 0; r < 2; ++r) {
        const int i = r * 256 + tid;
        const int pq = i >> 5, k = i & 31;
        int n = n0 + pq; if (n > NN - 1) n = NN - 1;   // clamped rows never stored
        idx_s[i] = idx[((size_t)(b * NN + n)) * KK + k];
    }
    __syncthreads();

    // ---- per (pos, class) inverse clamped count (128 threads) ----
    if (tid < TILE * CC) {
        const int pp = tid >> 3, c = tid & 7;
        int cnt = 0;
        #pragma unroll
        for (int k = 0; k < KK; ++k) cnt += (idx_s[pp * KK + k] == c) ? 1 : 0;
        inv_s[tid] = 1.0f / (float)(cnt > 1 ? cnt : 1);
    }
    __syncthreads();   // inv_s ready BEFORE the first per-position mean write

    // ---- phase 1: each wave owns 4 positions; 1KB-contiguous loads, 2-buffer ----
    {
        const int wv   = tid >> 6;        // wave 0..3
        const int lane = tid & 63;
        const int kofs = lane >> 4;       // which k within a 4-row chunk
        const int d4   = (lane & 15) * 4;

        // position pointers (clamped rows recomputed, never stored)
        const float4* xp[4];
        #pragma unroll
        for (int i = 0; i < 4; ++i) {
            int n = n0 + wv * 4 + i; if (n > NN - 1) n = NN - 1;
            xp[i] = (const float4*)(x + ((size_t)(b * NN + n)) * KK * DIN);
        }

        float4 acc[CC];
        float4 va[8], vb[8];

        // p0/p1 prefetched (16 x 1KB in flight), then alternate statically.
        pfw(va, xp[0], lane);
        pfw(vb, xp[1], lane);

        #pragma unroll
        for (int c = 0; c < CC; ++c) acc[c] = make_float4(0.f, 0.f, 0.f, 0.f);
        cbw(acc, va, &idx_s[(wv * 4 + 0) * KK], kofs);
        pfw(va, xp[2], lane);
        reduce_write(acc, &inv_s[(wv * 4 + 0) * CC],
                     &mean_s[((wv * 4 + 0) * CC) * MPAD], lane, d4);

        #pragma unroll
        for (int c = 0; c < CC; ++c) acc[c] = make_float4(0.f, 0.f, 0.f, 0.f);
        cbw(acc, vb, &idx_s[(wv * 4 + 1) * KK], kofs);
        pfw(vb, xp[3], lane);
        reduce_write(acc, &inv_s[(wv * 4 + 1) * CC],
                     &mean_s[((wv * 4 + 1) * CC) * MPAD], lane, d4);

        #pragma unroll
        for (int c = 0; c < CC; ++c) acc[c] = make_float4(0.f, 0.f, 0.f, 0.f);
        cbw(acc, va, &idx_s[(wv * 4 + 2) * KK], kofs);
        reduce_write(acc, &inv_s[(wv * 4 + 2) * CC],
                     &mean_s[((wv * 4 + 2) * CC) * MPAD], lane, d4);

        #pragma unroll
        for (int c = 0; c < CC; ++c) acc[c] = make_float4(0.f, 0.f, 0.f, 0.f);
        cbw(acc, vb, &idx_s[(wv * 4 + 3) * KK], kofs);
        reduce_write(acc, &inv_s[(wv * 4 + 3) * CC],
                     &mean_s[((wv * 4 + 3) * CC) * MPAD], lane, d4);
    }
    __syncthreads();

    // ---- phase 2 (unchanged from the 62.6us baseline) ----
    // thread = (ph = tid>>7 -> pos 8ph..8ph+7, c = (tid>>4)&7, o0 = (tid&15)*4).
    {
        const int ph = tid >> 7;
        const int c  = (tid >> 4) & 7;
        const int o0 = (tid & 15) * 4;

        float4 acc2[8];
        #pragma unroll
        for (int pp = 0; pp < 8; ++pp) acc2[pp] = make_float4(0.f, 0.f, 0.f, 0.f);

        if (USE_WT) {
            const float* __restrict__ Wtc = Wt + (size_t)c * DIN * DOUT + o0;
            #pragma unroll 1
            for (int dc = 0; dc < 16; ++dc) {       // dd = dc*4
                const float4 w0 = *(const float4*)(Wtc + (size_t)(dc * 4 + 0) * DOUT);
                const float4 w1 = *(const float4*)(Wtc + (size_t)(dc * 4 + 1) * DOUT);
                const float4 w2 = *(const float4*)(Wtc + (size_t)(dc * 4 + 2) * DOUT);
                const float4 w3 = *(const float4*)(Wtc + (size_t)(dc * 4 + 3) * DOUT);
                #pragma unroll
                for (int pp = 0; pp < 8; ++pp) {
                    const int pq = ph * 8 + pp;
                    const float4 m = *(const float4*)(&mean_s[(pq * CC + c) * MPAD + dc * 4]);
                    acc2[pp].x = fmaf(m.x, w0.x, acc2[pp].x);
                    acc2[pp].y = fmaf(m.x, w0.y, acc2[pp].y);
                    acc2[pp].z = fmaf(m.x, w0.z, acc2[pp].z);
                    acc2[pp].w = fmaf(m.x, w0.w, acc2[pp].w);
                    acc2[pp].x = fmaf(m.y, w1.x, acc2[pp].x);
                    acc2[pp].y = fmaf(m.y, w1.y, acc2[pp].y);
                    acc2[pp].z = fmaf(m.y, w1.z, acc2[pp].z);
                    acc2[pp].w = fmaf(m.y, w1.w, acc2[pp].w);
                    acc2[pp].x = fmaf(m.z, w2.x, acc2[pp].x);
                    acc2[pp].y = fmaf(m.z, w2.y, acc2[pp].y);
                    acc2[pp].z = fmaf(m.z, w2.z, acc2[pp].z);
                    acc2[pp].w = fmaf(m.z, w2.w, acc2[pp].w);
                    acc2[pp].x = fmaf(m.w, w3.x, acc2[pp].x);
                    acc2[pp].y = fmaf(m.w, w3.y, acc2[pp].y);
                    acc2[pp].z = fmaf(m.w, w3.z, acc2[pp].z);
                    acc2[pp].w = fmaf(m.w, w3.w, acc2[pp].w);
                }
            }
        } else {
            // fallback: raw W layout (scattered within wave, works without d_ws)
            const float* __restrict__ Wc = W + (size_t)c * DOUT * DIN;
            #pragma unroll 1
            for (int dc = 0; dc < 16; ++dc) {
                float4 w[4];
                #pragma unroll
                for (int j = 0; j < 4; ++j)
                    w[j] = *(const float4*)(Wc + (size_t)(o0 + j) * DIN + dc * 4);
                #pragma unroll
                for (int pp = 0; pp < 8; ++pp) {
                    const int pq = ph * 8 + pp;
                    const float4 m = *(const float4*)(&mean_s[(pq * CC + c) * MPAD + dc * 4]);
                    float* a = (float*)&acc2[pp];
                    #pragma unroll
                    for (int j = 0; j < 4; ++j) {
                        a[j] = fmaf(m.x, w[j].x, a[j]);
                        a[j] = fmaf(m.y, w[j].y, a[j]);
                        a[j] = fmaf(m.z, w[j].z, a[j]);
                        a[j] = fmaf(m.w, w[j].w, a[j]);
                    }
                }
            }
        }

        #pragma unroll
        for (int pp = 0; pp < 8; ++pp) {
            const int pq = ph * 8 + pp;
            const int nn = n0 + pq;
            if (nn < NN) {
                float4 r;
                r.x = fast_tanh(acc2[pp].x);
                r.y = fast_tanh(acc2[pp].y);
                r.z = fast_tanh(acc2[pp].z);
                r.w = fast_tanh(acc2[pp].w);
                *(float4*)(out + (((size_t)(b * NN + nn)) * CC + c) * DOUT + o0) = r;
            }
        }
    }
}

extern "C" void kernel_launch(void* const* d_in, const int* in_sizes, int n_in,
                              void* d_out, int out_size, void* d_ws, size_t ws_size,
                              hipStream_t stream) {
    const int*   idx = (const int*)d_in[0];    // clustered_index_topk [B,N,K] int32
    const float* x   = (const float*)d_in[1];  // weightedDinput_topk [B,N,K,DIN] f32
    const float* W   = (const float*)d_in[2];  // W [C,DOUT,DIN] f32
    float* out = (float*)d_out;                // [B,N,C,DOUT] f32
    float* Wt  = (float*)d_ws;                 // [C,DIN,DOUT] scratch
                                               // (ws poison fills are unconditional -> free)
    dim3 grid(NT, BB);   // 13 x 64 = 832 blocks
    dim3 block(256);
    const size_t wt_bytes = (size_t)CC * DIN * DOUT * sizeof(float);  // 128 KB
    if (ws_size >= wt_bytes) {
        transpose_W_kernel<<<dim3(CC), block, 0, stream>>>(W, Wt);
        ordered_gcn_kernel<true><<<grid, block, 0, stream>>>(idx, x, W, Wt, out);
    } else {
        ordered_gcn_kernel<false><<<grid, block, 0, stream>>>(idx, x, W, Wt, out);
    }
}